// Round 7
// baseline (392.596 us; speedup 1.0000x reference)
//
#include <hip/hip_runtime.h>
#include <limits.h>

#define HH 128
#define WW_ 128
#define HW 16384
#define NB 16
#define CF 192
#define H2 64
#define W2 64
#define NRUN 8192     // max runs: 128 rows * 64 runs/row
#define NCOMP 4096    // max 8-connected components in 128x128

typedef float vf4 __attribute__((ext_vector_type(4)));
typedef unsigned long long ull;

// ---------------------------------------------------------------------------
// Union-find on LDS parent array indexed by run id = (row<<6) | runIdxInRow.
// Links always go high->low id -> chains strictly decrease -> concurrent
// path halving is safe and terminating.
// ---------------------------------------------------------------------------

__device__ inline int uf_find(int* par, int x) {
    volatile int* vp = (volatile int*)par;
    int p = vp[x];
    while (p != x) {
        int g = vp[p];
        vp[x] = g;
        x = g;
        p = vp[x];
    }
    return x;
}

__device__ inline void uf_union(int* par, int a, int b) {
    int ra = uf_find(par, a);
    int rb = uf_find(par, b);
    while (ra != rb) {
        if (ra < rb) { int t = ra; ra = rb; rb = t; }
        int old = atomicCAS(&par[ra], ra, rb);
        if (old == ra) return;
        ra = uf_find(par, old);
        rb = uf_find(par, rb);
    }
}

// walk to terminal: claimed marker (>=NRUN) or unclaimed root id.
// Safe under concurrent flatten/claim writes (values only jump toward roots).
__device__ inline int walk_term(int* par, int x) {
    volatile int* vp = (volatile int*)par;
    int p = vp[x];
    while (p < NRUN && p != x) { x = p; p = vp[x]; }
    return (p >= NRUN) ? p : x;
}

// ---------------------------------------------------------------------------
// 128-bit row mask helpers (lo = cols 0..63, hi = cols 64..127)
// ---------------------------------------------------------------------------

__device__ inline int getbit2(ull lo, ull hi, int c) {
    return (int)(((c < 64) ? (lo >> c) : (hi >> (c - 64))) & 1ULL);
}

__device__ inline int leading_ones(ull v) {
    ull nv = ~v;
    return (nv == 0ULL) ? 64 : __clzll(nv);
}

__device__ inline int trailing_ones(ull v) {
    ull nv = ~v;
    return (nv == 0ULL) ? 64 : (__ffsll(nv) - 1);
}

// column of the start of the fg run containing column c (bit c must be set)
__device__ inline int run_start_col(ull lo, ull hi, int c) {
    if (c < 64) {
        int ones = leading_ones(lo << (63 - c));
        return c - ones + 1;
    }
    int ones = leading_ones(hi << (127 - c));
    int rs = c - ones + 1;
    if (rs == 64) rs -= leading_ones(lo);
    return rs;
}

// column of the end of the fg run containing column c (bit c must be set)
__device__ inline int run_end_col(ull lo, ull hi, int c) {
    if (c >= 64) {
        return c + trailing_ones(hi >> (c - 64)) - 1;
    }
    int e = c + trailing_ones(lo >> c) - 1;
    if (e == 63) e += trailing_ones(hi);
    return e;
}

// 0-based index of the run starting at column cs (cs must be a run start)
__device__ inline int run_index(ull rs_lo, ull rs_hi, int cs) {
    if (cs < 64)  return __popcll(rs_lo & ((1ULL << cs) - 1ULL));
    if (cs == 64) return __popcll(rs_lo);
    return __popcll(rs_lo) + __popcll(rs_hi & ((1ULL << (cs - 64)) - 1ULL));
}

// 128-bit mask of bits [a, b] inclusive, 0 <= a <= b <= 127
__device__ inline void span_mask(int a, int b, ull& mlo, ull& mhi) {
    ull one = ~0ULL;
    int bl = (b < 63) ? b : 63;
    mlo = (a <= 63) ? (((bl == 63) ? one : ((1ULL << (bl + 1)) - 1)) & ~((1ULL << a) - 1)) : 0ULL;
    if (b >= 64) {
        int a2 = (a >= 64) ? a - 64 : 0;
        int b2 = b - 64;
        mhi = ((b2 == 63) ? one : ((1ULL << (b2 + 1)) - 1)) & ~((1ULL << a2) - 1);
    } else mhi = 0ULL;
}

__device__ inline void top3_ins(float s, int id, int x,
    float& s0, float& s1, float& s2,
    int& i0, int& i1, int& i2,
    int& x0, int& x1, int& x2)
{
    if (x < 0) return;
    if (s > s0 || (s == s0 && id < i0)) {
        s2 = s1; i2 = i1; x2 = x1;
        s1 = s0; i1 = i0; x1 = x0;
        s0 = s;  i0 = id; x0 = x;
    } else if (s > s1 || (s == s1 && id < i1)) {
        s2 = s1; i2 = i1; x2 = x1;
        s1 = s;  i1 = id; x1 = x;
    } else if (s > s2 || (s == s2 && id < i2)) {
        s2 = s;  i2 = id; x2 = x;
    }
}

// ---------------------------------------------------------------------------
// Kernel 1: one block per image. Run-based union-find CCL + stats + top-3 +
// bbox, all in LDS. 6 barriers total:
//  P0 one-wave-per-row mask build + parent init | B1
//  P2 run-centric unions (span-intersect upper run-start mask)  | B2
//  P3 merged flatten+dense-claim (marker >= NRUN)               | B3
//  stats init for n entries only                                | B4
//  P4 per-run stats, 7 LDS atomics per run                      | B5
//  P5 top-3 scan + wave butterfly partials                      | B6
//  tid0 final merge + K rules + bbox write
// ---------------------------------------------------------------------------

__global__ __launch_bounds__(1024) void ccl_kernel(
    const float* __restrict__ prob, int* __restrict__ bbox)
{
    __shared__ int parent[NRUN];          // 32 KB
    __shared__ ull rowmask[HH][2];        // 2 KB
    __shared__ ull rsmask[HH][2];         // 2 KB
    __shared__ int nrunrow[HH];           // 0.5 KB
    __shared__ int   lcnt[NCOMP];         // 16 KB
    __shared__ float lconf[NCOMP];        // 16 KB
    __shared__ int lminr[NCOMP], lmaxr[NCOMP];
    __shared__ int lminc[NCOMP], lmaxc[NCOMP];
    __shared__ int lmaxid[NCOMP];         // 5 x 16 KB
    __shared__ int snroots;
    __shared__ float wss[48];
    __shared__ int wid_[48], wrx[48];

    const int b = blockIdx.x;
    const int tid = threadIdx.x;
    const int lane = tid & 63;
    const float* p = prob + (size_t)b * HW;

    if (tid == 0) snroots = 0;

    // P0: one wave per row: masks + run-start masks + run counts in one pass
    {
        int wv = tid >> 6;                    // 16 waves
        #pragma unroll
        for (int k = 0; k < 8; ++k) {
            int row = wv * 8 + k;
            const float* rp = p + (row << 7);
            ull m0 = __ballot(rp[lane] > 0.5f);
            ull m1 = __ballot(rp[64 + lane] > 0.5f);
            if (lane == 0) {
                rowmask[row][0] = m0; rowmask[row][1] = m1;
                ull rs_lo = m0 & ~(m0 << 1);
                ull rs_hi = m1 & ~((m1 << 1) | (m0 >> 63));
                rsmask[row][0] = rs_lo; rsmask[row][1] = rs_hi;
                nrunrow[row] = __popcll(rs_lo) + __popcll(rs_hi);
            }
        }
        #pragma unroll
        for (int k = 0; k < NRUN / 1024; ++k)
            parent[k * 1024 + tid] = k * 1024 + tid;
    }
    __syncthreads();

    // P2: run-centric unions. Thread = one 16-col window of one row; for each
    // run starting in the window, intersect span [c-1, e+1] with the upper
    // row: the run covering span-start (if fg) + every upper run START inside
    // the span. Exactly one union per overlapping (run, upper-run) pair.
    {
        int row = tid >> 3;
        int w0 = (tid & 7) * 16;
        if (row > 0) {
            ull lo = rowmask[row][0], hi = rowmask[row][1];
            ull rs_lo = rsmask[row][0], rs_hi = rsmask[row][1];
            ull seg = ((w0 < 64) ? (rs_lo >> w0) : (rs_hi >> (w0 - 64))) & 0xFFFFULL;
            if (seg) {
                ull ulo = rowmask[row - 1][0], uhi = rowmask[row - 1][1];
                ull urs_lo = rsmask[row - 1][0], urs_hi = rsmask[row - 1][1];
                int ub = (row - 1) << 6;
                while (seg) {
                    int c = w0 + (__ffsll(seg) - 1);
                    seg &= seg - 1;
                    int e = run_end_col(lo, hi, c);
                    int rid = (row << 6) + run_index(rs_lo, rs_hi, c);
                    int s0 = (c > 0) ? c - 1 : 0;
                    int s1 = (e < 127) ? e + 1 : 127;
                    if (getbit2(ulo, uhi, s0))
                        uf_union(parent, rid,
                                 ub + run_index(urs_lo, urs_hi, run_start_col(ulo, uhi, s0)));
                    if (s1 > s0) {
                        ull mlo, mhi;
                        span_mask(s0 + 1, s1, mlo, mhi);
                        ull h_lo = urs_lo & mlo, h_hi = urs_hi & mhi;
                        while (h_lo) {
                            int cs = __ffsll(h_lo) - 1; h_lo &= h_lo - 1;
                            uf_union(parent, rid, ub + run_index(urs_lo, urs_hi, cs));
                        }
                        while (h_hi) {
                            int cs = 64 + __ffsll(h_hi) - 1; h_hi &= h_hi - 1;
                            uf_union(parent, rid, ub + run_index(urs_lo, urs_hi, cs));
                        }
                    }
                }
            }
        }
    }
    __syncthreads();

    // P3: merged flatten + dense-index claim. Roots get parent = NRUN+idx
    // (wave-aggregated atomic); non-roots store their terminal (marker or
    // root id -> <=1 hop from a marker after the barrier).
    for (int rid = tid; rid < NRUN; rid += 1024) {
        bool valid = (rid & 63) < nrunrow[rid >> 6];
        bool isroot = valid && parent[rid] == rid;
        ull m = __ballot(isroot);
        if (m) {
            int baseIdx = 0;
            if (lane == 0) baseIdx = atomicAdd(&snroots, __popcll(m));
            baseIdx = __shfl(baseIdx, 0);
            if (isroot)
                parent[rid] = NRUN + baseIdx + __popcll(m & ((1ULL << lane) - 1ULL));
        }
        if (valid && !isroot)
            parent[rid] = walk_term(parent, rid);
    }
    __syncthreads();

    // stats init: only the n live entries
    const int n = snroots;
    for (int j = tid; j < n; j += 1024) {
        lcnt[j] = 0; lconf[j] = 0.f;
        lminr[j] = INT_MAX; lmaxr[j] = -1;
        lminc[j] = INT_MAX; lmaxc[j] = -1;
        lmaxid[j] = 0;
    }
    __syncthreads();

    // P4: per-run stats (7 LDS atomics per run); conf sum reads global p
    // (L2-warm from P0)
    {
        int row = tid >> 3;
        int w0 = (tid & 7) * 16;
        ull lo = rowmask[row][0], hi = rowmask[row][1];
        ull rs_lo = rsmask[row][0], rs_hi = rsmask[row][1];
        ull seg = ((w0 < 64) ? (rs_lo >> w0) : (rs_hi >> (w0 - 64))) & 0xFFFFULL;
        while (seg) {
            int c = w0 + (__ffsll(seg) - 1);
            seg &= seg - 1;
            int e = run_end_col(lo, hi, c);
            int rid = (row << 6) + run_index(rs_lo, rs_hi, c);
            int v = parent[rid];
            int idx = (v >= NRUN) ? (v - NRUN) : (parent[v] - NRUN);
            float s = 0.f;
            for (int j = c; j <= e; ++j) s += p[(row << 7) + j];
            atomicAdd(&lcnt[idx], e - c + 1);
            atomicAdd(&lconf[idx], s);
            atomicMin(&lminr[idx], row);
            atomicMax(&lmaxr[idx], row);
            atomicMin(&lminc[idx], c);
            atomicMax(&lmaxc[idx], e);
            atomicMax(&lmaxid[idx], (row << 7) + e + 1);   // stored as idx+1
        }
    }
    __syncthreads();

    // P5: top-3 by (mean_conf desc, segment-id asc): thread scan -> wave
    // butterfly -> partials
    {
        float s0 = -INFINITY, s1 = -INFINITY, s2 = -INFINITY;
        int i0 = INT_MAX, i1 = INT_MAX, i2 = INT_MAX;
        int x0 = -1, x1 = -1, x2 = -1;
        for (int j = tid; j < n; j += 1024) {
            float s = lconf[j] / (float)lcnt[j];
            top3_ins(s, lmaxid[j], j, s0, s1, s2, i0, i1, i2, x0, x1, x2);
        }
        for (int off = 32; off; off >>= 1) {
            float bs0 = __shfl_xor(s0, off), bs1 = __shfl_xor(s1, off), bs2 = __shfl_xor(s2, off);
            int bi0 = __shfl_xor(i0, off), bi1 = __shfl_xor(i1, off), bi2 = __shfl_xor(i2, off);
            int bx0 = __shfl_xor(x0, off), bx1 = __shfl_xor(x1, off), bx2 = __shfl_xor(x2, off);
            top3_ins(bs0, bi0, bx0, s0, s1, s2, i0, i1, i2, x0, x1, x2);
            top3_ins(bs1, bi1, bx1, s0, s1, s2, i0, i1, i2, x0, x1, x2);
            top3_ins(bs2, bi2, bx2, s0, s1, s2, i0, i1, i2, x0, x1, x2);
        }
        if (lane == 0) {
            int w = tid >> 6;
            wss[w * 3 + 0] = s0; wid_[w * 3 + 0] = i0; wrx[w * 3 + 0] = x0;
            wss[w * 3 + 1] = s1; wid_[w * 3 + 1] = i1; wrx[w * 3 + 1] = x1;
            wss[w * 3 + 2] = s2; wid_[w * 3 + 2] = i2; wrx[w * 3 + 2] = x2;
        }
    }
    __syncthreads();

    if (tid == 0) {
        float t0 = -INFINITY, t1 = -INFINITY, t2 = -INFINITY;
        int ti0 = INT_MAX, ti1 = INT_MAX, ti2 = INT_MAX;
        int tx0 = -1, tx1 = -1, tx2 = -1;
        for (int t = 0; t < 48; ++t)
            top3_ins(wss[t], wid_[t], wrx[t], t0, t1, t2, ti0, ti1, ti2, tx0, tx1, tx2);
        int K = n;
        int roots[3];
        if (K >= 3)      { roots[0] = tx0; roots[1] = tx1; roots[2] = tx2; }
        else if (K == 2) { roots[0] = tx0; roots[1] = tx0; roots[2] = tx1; }
        else             { roots[0] = tx0; roots[1] = tx0; roots[2] = tx0; }
        for (int slot = 0; slot < 3; ++slot) {
            int mr, h, mc, w;
            if (K == 0) { mr = 0; h = HH; mc = 0; w = WW_; }
            else {
                int rt = roots[slot];
                mr = lminr[rt]; h = lmaxr[rt] + 1 - mr;
                mc = lminc[rt]; w = lmaxc[rt] + 1 - mc;
            }
            int* o = bbox + (b * 3 + slot) * 4;
            o[0] = mr; o[1] = h; o[2] = mc; o[3] = w;
        }
    }
}

// ---------------------------------------------------------------------------
// Kernel 2: nearest-neighbor crop-resize gather. 2 x float4 per thread,
// bbox/row resolved once. out[b, slot*192+c, y, x] =
//   feat[b, c, mr + (y*h)>>6, mc + (x*w)>>6]
// ---------------------------------------------------------------------------

__global__ __launch_bounds__(256) void crop_kernel(
    const float* __restrict__ feat, const int* __restrict__ bbox,
    float* __restrict__ out)
{
    const int gid = blockIdx.x * 256 + threadIdx.x;   // 4,718,592 threads
    const int o4 = gid * 2;          // first of 2 consecutive float4 outputs
    const int x4 = o4 & 15;          // even; o4+1 shares y and t
    const int y  = (o4 >> 4) & 63;
    const int t  = o4 >> 10;         // (b*3+slot)*192 + c
    const int c  = t % CF;
    const int bs = t / CF;
    const int* bb = bbox + bs * 4;
    const int mr = bb[0], h = bb[1], mc = bb[2], w = bb[3];
    const int r = mr + ((y * h) >> 6);
    const int bimg = bs / 3;
    const float* row = feat + (((size_t)bimg * CF + c) * HH + r) * WW_;
    const int x = x4 * 4;
    vf4 v0, v1;
    v0.x = row[mc + (((x + 0) * w) >> 6)];
    v0.y = row[mc + (((x + 1) * w) >> 6)];
    v0.z = row[mc + (((x + 2) * w) >> 6)];
    v0.w = row[mc + (((x + 3) * w) >> 6)];
    v1.x = row[mc + (((x + 4) * w) >> 6)];
    v1.y = row[mc + (((x + 5) * w) >> 6)];
    v1.z = row[mc + (((x + 6) * w) >> 6)];
    v1.w = row[mc + (((x + 7) * w) >> 6)];
    __builtin_nontemporal_store(v0, (vf4*)out + o4);
    __builtin_nontemporal_store(v1, (vf4*)out + o4 + 1);
}

// ---------------------------------------------------------------------------

extern "C" void kernel_launch(void* const* d_in, const int* in_sizes, int n_in,
                              void* d_out, int out_size, void* d_ws, size_t ws_size,
                              hipStream_t stream) {
    const float* prob = (const float*)d_in[0];   // [16,1,128,128]
    const float* feat = (const float*)d_in[1];   // [16,192,128,128]
    float* out = (float*)d_out;                  // [16,576,64,64]

    int* bbox = (int*)d_ws;                      // [16][3][4] ints, fully written

    hipLaunchKernelGGL(ccl_kernel, dim3(NB), dim3(1024), 0, stream,
                       prob, bbox);
    const int total4 = NB * 3 * CF * H2 * (W2 / 4);   // 9,437,184 float4s
    hipLaunchKernelGGL(crop_kernel, dim3(total4 / 512), dim3(256), 0, stream,
                       feat, bbox, out);
}